// Round 1
// baseline (471.705 us; speedup 1.0000x reference)
//
#include <hip/hip_runtime.h>
#include <hip/hip_bf16.h>
#include <cstdint>
#include <cstddef>

using bf16 = __hip_bfloat16;
typedef __attribute__((ext_vector_type(8))) __bf16 bf16x8;
typedef __attribute__((ext_vector_type(4))) float f32x4;

typedef const __attribute__((address_space(1))) void CGV;
typedef __attribute__((address_space(3))) void LDSV;

__device__ __forceinline__ void gload_lds16(const void* g, void* l) {
    // wave-uniform LDS base; HW adds lane*16 bytes. 16B/lane direct global->LDS.
    __builtin_amdgcn_global_load_lds((CGV*)g, (LDSV*)l, 16, 0, 0);
}

__device__ __forceinline__ float bits2f(unsigned short u) {
    return __uint_as_float(((unsigned)u) << 16);
}
__device__ __forceinline__ unsigned short f2bits(float f) {
    return __builtin_bit_cast(unsigned short, __float2bfloat16(f));
}

// ---------------------------------------------------------------------------
// cast x (fp32) -> bf16, vectorized float4 -> ushort4
__global__ void cast_f32_bf16(const float4* __restrict__ in, ushort4* __restrict__ out, int n4) {
    int i = blockIdx.x * 256 + threadIdx.x;
    if (i < n4) {
        float4 f = in[i];
        ushort4 u;
        u.x = f2bits(f.x); u.y = f2bits(f.y); u.z = f2bits(f.z); u.w = f2bits(f.w);
        out[i] = u;
    }
}

// ---------------------------------------------------------------------------
// transpose+cast the three projection weights: W (K=1024,N=1024) fp32 -> Wt (N,K) bf16
__global__ void transpose_cast(const float* __restrict__ A, const float* __restrict__ B,
                               const float* __restrict__ C, bf16* __restrict__ Wt3) {
    const float* W = (blockIdx.z == 0) ? A : (blockIdx.z == 1) ? B : C;
    bf16* O = Wt3 + (size_t)blockIdx.z * (1024 * 1024);
    __shared__ float tile[32][33];
    int x = blockIdx.x * 32 + threadIdx.x;   // n
    int y0 = blockIdx.y * 32;                // k base
    for (int i = threadIdx.y; i < 32; i += 8)
        tile[i][threadIdx.x] = W[(size_t)(y0 + i) * 1024 + x];
    __syncthreads();
    int xo = blockIdx.y * 32 + threadIdx.x;  // k
    int yo = blockIdx.x * 32;                // n base
    for (int i = threadIdx.y; i < 32; i += 8)
        O[(size_t)(yo + i) * 1024 + xo] = __float2bfloat16(tile[threadIdx.x][i]);
}

// ---------------------------------------------------------------------------
// G = RF @ RF^T : (64,256)x(256,64) -> (64,64) fp32
__global__ void g_kernel(const float* __restrict__ RF, float* __restrict__ G) {
    int o = blockIdx.x * 256 + threadIdx.x;   // 0..4095
    int i = o >> 6, j = o & 63;
    const float4* a = (const float4*)(RF + (size_t)i * 256);
    const float4* b = (const float4*)(RF + (size_t)j * 256);
    float s = 0.f;
    for (int f = 0; f < 64; f++) {
        float4 x = a[f], y = b[f];
        s += x.x * y.x + x.y * y.y + x.z * y.z + x.w * y.w;
    }
    G[o] = s;
}

// ---------------------------------------------------------------------------
// Q/K/V projection GEMM: C = Xb @ W, 16384x1024x1024, bf16 MFMA 16x16x32.
// grid (8, 128, 3): z picks Wq/Wk/Wv; phi(x)=x>0?x+1:exp(x) fused for z<2.
__global__ __launch_bounds__(256, 2) void gemm_qkv(
    const bf16* __restrict__ X, const bf16* __restrict__ Wt3,
    const float* __restrict__ bq, const float* __restrict__ bk, const float* __restrict__ bv,
    bf16* __restrict__ Qo, bf16* __restrict__ Ko, bf16* __restrict__ Vo)
{
    __shared__ bf16 As[128 * 64];
    __shared__ bf16 Bs[128 * 64];
    const int z = blockIdx.z;
    const int n0 = blockIdx.x * 128;
    const int m0 = blockIdx.y * 128;
    const int tid = threadIdx.x;
    const int w = tid >> 6, lane = tid & 63;
    const int lr = lane >> 3, lc = lane & 7;     // staging: 8 rows x 8 chunks(16B)
    const bf16* Wt = Wt3 + (size_t)z * (1024 * 1024);

    const bf16* ag = X  + (size_t)(m0 + w * 32 + lr) * 1024 + lc * 8;
    const bf16* bg = Wt + (size_t)(n0 + w * 32 + lr) * 1024 + lc * 8;
    bf16* al = As + (w * 32) * 64;
    bf16* bl = Bs + (w * 32) * 64;

    f32x4 acc[4][4];
#pragma unroll
    for (int i = 0; i < 4; i++)
#pragma unroll
        for (int j = 0; j < 4; j++) acc[i][j] = (f32x4){0.f, 0.f, 0.f, 0.f};

    const int lm = lane & 15, quad = lane >> 4;
    const bf16* Ab = As + ((w >> 1) * 64 + lm) * 64 + quad * 8;
    const bf16* Bb = Bs + ((w & 1) * 64 + lm) * 64 + quad * 8;

    for (int k0 = 0; k0 < 1024; k0 += 64) {
#pragma unroll
        for (int j = 0; j < 4; j++) {
            gload_lds16(ag + (size_t)j * 8 * 1024 + k0, al + j * 8 * 64);
            gload_lds16(bg + (size_t)j * 8 * 1024 + k0, bl + j * 8 * 64);
        }
        __syncthreads();
#pragma unroll
        for (int kk = 0; kk < 64; kk += 32) {
            bf16x8 a[4], b[4];
#pragma unroll
            for (int i = 0; i < 4; i++) a[i] = *(const bf16x8*)(Ab + i * 16 * 64 + kk);
#pragma unroll
            for (int i = 0; i < 4; i++) b[i] = *(const bf16x8*)(Bb + i * 16 * 64 + kk);
#pragma unroll
            for (int mi = 0; mi < 4; mi++)
#pragma unroll
                for (int ni = 0; ni < 4; ni++)
                    acc[mi][ni] = __builtin_amdgcn_mfma_f32_16x16x32_bf16(
                        a[mi], b[ni], acc[mi][ni], 0, 0, 0);
        }
        __syncthreads();
    }

    const float* bias = (z == 0) ? bq : (z == 1) ? bk : bv;
    bf16* Out = (z == 0) ? Qo : (z == 1) ? Ko : Vo;
    const int wr = (w >> 1) * 64, wc = (w & 1) * 64;
#pragma unroll
    for (int ni = 0; ni < 4; ni++) {
        int col = n0 + wc + ni * 16 + lm;
        float bs = bias[col];
#pragma unroll
        for (int mi = 0; mi < 4; mi++) {
            int row0 = m0 + wr + mi * 16 + quad * 4;
#pragma unroll
            for (int r = 0; r < 4; r++) {
                float v = acc[mi][ni][r] + bs;
                if (z != 2) v = (v > 0.f) ? (v + 1.f) : __expf(v);
                Out[(size_t)(row0 + r) * 1024 + col] = __float2bfloat16(v);
            }
        }
    }
}

// ---------------------------------------------------------------------------
// S[b,h] = phi(k)^T @ v per (b,h): 64x64 fp32, K-split over n (8 splits of 512).
// grid (64, 8), block 256. Each thread: 4x4 outer-product accumulation.
__global__ __launch_bounds__(256) void s_kernel(const unsigned short* __restrict__ Kp,
                                                const unsigned short* __restrict__ Vp,
                                                float* __restrict__ Spart)
{
    int bh = blockIdx.x;            // b*16 + h
    int split = blockIdx.y;         // 0..7
    int b = bh >> 4, h = bh & 15;
    int t = threadIdx.x;
    int eb = (t >> 4) * 4, db = (t & 15) * 4;
    size_t rowbase = ((size_t)b * 4096 + (size_t)split * 512) * 1024 + h * 64;
    const unsigned short* kp = Kp + rowbase + eb;
    const unsigned short* vp = Vp + rowbase + db;
    float acc[4][4];
#pragma unroll
    for (int i = 0; i < 4; i++)
#pragma unroll
        for (int j = 0; j < 4; j++) acc[i][j] = 0.f;

    for (int n = 0; n < 512; n++) {
        ushort4 ku = *(const ushort4*)kp;
        ushort4 vu = *(const ushort4*)vp;
        float kf[4] = {bits2f(ku.x), bits2f(ku.y), bits2f(ku.z), bits2f(ku.w)};
        float vf[4] = {bits2f(vu.x), bits2f(vu.y), bits2f(vu.z), bits2f(vu.w)};
#pragma unroll
        for (int i = 0; i < 4; i++)
#pragma unroll
            for (int j = 0; j < 4; j++) acc[i][j] += kf[i] * vf[j];
        kp += 1024; vp += 1024;
    }
    float* sp = Spart + ((size_t)split * 64 + bh) * 4096;
#pragma unroll
    for (int i = 0; i < 4; i++)
#pragma unroll
        for (int j = 0; j < 4; j++) sp[(eb + i) * 64 + db + j] = acc[i][j];
}

// reduce the 8 K-split partials: S[bh][4096] = sum_s Spart[s][bh][4096]
__global__ void reduce_s(const float* __restrict__ Spart, float* __restrict__ S) {
    int bh = blockIdx.x, t = threadIdx.x;
    for (int v = 0; v < 4; v++) {
        int idx = v * 1024 + t * 4;
        float4 a = {0.f, 0.f, 0.f, 0.f};
        for (int s = 0; s < 8; s++) {
            float4 p = *(const float4*)&Spart[((size_t)s * 64 + bh) * 4096 + idx];
            a.x += p.x; a.y += p.y; a.z += p.z; a.w += p.w;
        }
        *(float4*)&S[(size_t)bh * 4096 + idx] = a;
    }
}

// M[b,h] = G @ S[b,h] : 64x64x64 per bh. grid 64, block 256.
__global__ __launch_bounds__(256) void m_kernel(const float* __restrict__ S,
                                                const float* __restrict__ G,
                                                float* __restrict__ M)
{
    __shared__ float Sl[4096];
    int bh = blockIdx.x, t = threadIdx.x;
    for (int i = t; i < 4096; i += 256) Sl[i] = S[(size_t)bh * 4096 + i];
    __syncthreads();
    int e = t >> 2, d0 = (t & 3) * 16;
    float acc[16];
#pragma unroll
    for (int j = 0; j < 16; j++) acc[j] = 0.f;
    for (int ep = 0; ep < 64; ep++) {
        float g = G[e * 64 + ep];
#pragma unroll
        for (int j = 0; j < 16; j++) acc[j] += g * Sl[ep * 64 + d0 + j];
    }
#pragma unroll
    for (int j = 0; j < 16; j++) M[(size_t)bh * 4096 + e * 64 + d0 + j] = acc[j];
}

// Fold M into Wo: Wo2t[b][c][h*64+e] = sum_d M[b,h][e][d] * Wo[h*64+d][c]
// (written transposed (N,K) for the final GEMM). grid 256 = (b,h,cblk), block 256.
__global__ __launch_bounds__(256) void fold_kernel(const float* __restrict__ M,
                                                   const float* __restrict__ Wo,
                                                   bf16* __restrict__ Wo2t)
{
    int x = blockIdx.x;
    int b = x >> 6, h = (x >> 2) & 15, cb = x & 3;
    __shared__ float Ml[4096];   // transposed: Ml[d*64 + e]
    int t = threadIdx.x;
    for (int i = t; i < 4096; i += 256) {
        int e = i >> 6, d = i & 63;
        Ml[d * 64 + e] = M[((size_t)b * 16 + h) * 4096 + i];
    }
    __syncthreads();
    int c = cb * 256 + t;
    float acc[64];
#pragma unroll
    for (int e = 0; e < 64; e++) acc[e] = 0.f;
    for (int d = 0; d < 64; d++) {
        float wo = Wo[(size_t)(h * 64 + d) * 1024 + c];
#pragma unroll
        for (int e = 0; e < 64; e++) acc[e] += Ml[d * 64 + e] * wo;
    }
    unsigned* outp = (unsigned*)(Wo2t + ((size_t)b * 1024 + c) * 1024 + h * 64);
#pragma unroll
    for (int e = 0; e < 64; e += 2) {
        unsigned lo = f2bits(acc[e]);
        unsigned hi = f2bits(acc[e + 1]);
        outp[e >> 1] = lo | (hi << 16);
    }
}

// ---------------------------------------------------------------------------
// Final GEMM: out = phi(q) @ Wo'_b + bo, fp32 output. grid (8,128).
__global__ __launch_bounds__(256, 2) void gemm_out(
    const bf16* __restrict__ Qp, const bf16* __restrict__ Wo2t,
    const float* __restrict__ bo, float* __restrict__ Out)
{
    __shared__ bf16 As[128 * 64];
    __shared__ bf16 Bs[128 * 64];
    const int n0 = blockIdx.x * 128;
    const int m0 = blockIdx.y * 128;
    const int tid = threadIdx.x;
    const int w = tid >> 6, lane = tid & 63;
    const int lr = lane >> 3, lc = lane & 7;
    const bf16* Wt = Wo2t + (size_t)(m0 >> 12) * (1024 * 1024);   // per-batch weights

    const bf16* ag = Qp + (size_t)(m0 + w * 32 + lr) * 1024 + lc * 8;
    const bf16* bg = Wt + (size_t)(n0 + w * 32 + lr) * 1024 + lc * 8;
    bf16* al = As + (w * 32) * 64;
    bf16* bl = Bs + (w * 32) * 64;

    f32x4 acc[4][4];
#pragma unroll
    for (int i = 0; i < 4; i++)
#pragma unroll
        for (int j = 0; j < 4; j++) acc[i][j] = (f32x4){0.f, 0.f, 0.f, 0.f};

    const int lm = lane & 15, quad = lane >> 4;
    const bf16* Ab = As + ((w >> 1) * 64 + lm) * 64 + quad * 8;
    const bf16* Bb = Bs + ((w & 1) * 64 + lm) * 64 + quad * 8;

    for (int k0 = 0; k0 < 1024; k0 += 64) {
#pragma unroll
        for (int j = 0; j < 4; j++) {
            gload_lds16(ag + (size_t)j * 8 * 1024 + k0, al + j * 8 * 64);
            gload_lds16(bg + (size_t)j * 8 * 1024 + k0, bl + j * 8 * 64);
        }
        __syncthreads();
#pragma unroll
        for (int kk = 0; kk < 64; kk += 32) {
            bf16x8 a[4], b[4];
#pragma unroll
            for (int i = 0; i < 4; i++) a[i] = *(const bf16x8*)(Ab + i * 16 * 64 + kk);
#pragma unroll
            for (int i = 0; i < 4; i++) b[i] = *(const bf16x8*)(Bb + i * 16 * 64 + kk);
#pragma unroll
            for (int mi = 0; mi < 4; mi++)
#pragma unroll
                for (int ni = 0; ni < 4; ni++)
                    acc[mi][ni] = __builtin_amdgcn_mfma_f32_16x16x32_bf16(
                        a[mi], b[ni], acc[mi][ni], 0, 0, 0);
        }
        __syncthreads();
    }

    const int wr = (w >> 1) * 64, wc = (w & 1) * 64;
#pragma unroll
    for (int ni = 0; ni < 4; ni++) {
        int col = n0 + wc + ni * 16 + lm;
        float bs = bo[col];
#pragma unroll
        for (int mi = 0; mi < 4; mi++) {
            int row0 = m0 + wr + mi * 16 + quad * 4;
#pragma unroll
            for (int r = 0; r < 4; r++)
                Out[(size_t)(row0 + r) * 1024 + col] = acc[mi][ni][r] + bs;
        }
    }
}

// ---------------------------------------------------------------------------
extern "C" void kernel_launch(void* const* d_in, const int* in_sizes, int n_in,
                              void* d_out, int out_size, void* d_ws, size_t ws_size,
                              hipStream_t stream) {
    const float* x  = (const float*)d_in[0];
    const float* Wq = (const float*)d_in[1];
    const float* bq = (const float*)d_in[2];
    const float* Wk = (const float*)d_in[3];
    const float* bk = (const float*)d_in[4];
    const float* Wv = (const float*)d_in[5];
    const float* bv = (const float*)d_in[6];
    const float* Wo = (const float*)d_in[7];
    const float* bo = (const float*)d_in[8];
    const float* RF = (const float*)d_in[9];
    float* out = (float*)d_out;

    char* ws = (char*)d_ws;
    bf16*  Xb    = (bf16*) (ws);                           // 32 MB
    bf16*  Qp    = (bf16*) (ws + ((size_t)32  << 20));     // 32 MB
    bf16*  Kp    = (bf16*) (ws + ((size_t)64  << 20));     // 32 MB
    bf16*  Vp    = (bf16*) (ws + ((size_t)96  << 20));     // 32 MB
    bf16*  Wt3   = (bf16*) (ws + ((size_t)128 << 20));     // 6 MB
    bf16*  Wo2t  = (bf16*) (ws + ((size_t)134 << 20));     // 8 MB
    float* Spart = (float*)(ws + ((size_t)142 << 20));     // 8 MB
    float* S     = (float*)(ws + ((size_t)150 << 20));     // 1 MB
    float* Mm    = (float*)(ws + ((size_t)151 << 20));     // 1 MB
    float* G     = (float*)(ws + ((size_t)152 << 20));     // 16 KB

    cast_f32_bf16<<<16384, 256, 0, stream>>>((const float4*)x, (ushort4*)Xb, 4194304);
    transpose_cast<<<dim3(32, 32, 3), dim3(32, 8), 0, stream>>>(Wq, Wk, Wv, Wt3);
    g_kernel<<<16, 256, 0, stream>>>(RF, G);
    gemm_qkv<<<dim3(8, 128, 3), 256, 0, stream>>>(Xb, Wt3, bq, bk, bv, Qp, Kp, Vp);
    s_kernel<<<dim3(64, 8), 256, 0, stream>>>((const unsigned short*)Kp,
                                              (const unsigned short*)Vp, Spart);
    reduce_s<<<64, 256, 0, stream>>>(Spart, S);
    m_kernel<<<64, 256, 0, stream>>>(S, G, Mm);
    fold_kernel<<<256, 256, 0, stream>>>(Mm, Wo, Wo2t);
    gemm_out<<<dim3(8, 128), 256, 0, stream>>>(Qp, Wo2t, bo, out);
}

// Round 2
// 394.369 us; speedup vs baseline: 1.1961x; 1.1961x over previous
//
#include <hip/hip_runtime.h>
#include <hip/hip_bf16.h>
#include <cstdint>
#include <cstddef>

using bf16 = __hip_bfloat16;
typedef __attribute__((ext_vector_type(8))) __bf16 bf16x8;
typedef __attribute__((ext_vector_type(4))) float f32x4;

typedef const __attribute__((address_space(1))) void CGV;
typedef __attribute__((address_space(3))) void LDSV;

__device__ __forceinline__ void gload_lds16(const void* g, void* l) {
    // wave-uniform LDS base; HW writes lane i's 16B to base + i*16.
    __builtin_amdgcn_global_load_lds((CGV*)g, (LDSV*)l, 16, 0, 0);
}

__device__ __forceinline__ float bits2f(unsigned short u) {
    return __uint_as_float(((unsigned)u) << 16);
}
__device__ __forceinline__ unsigned short f2bits(float f) {
    return __builtin_bit_cast(unsigned short, __float2bfloat16(f));
}

// ---------------------------------------------------------------------------
// cast x (fp32) -> bf16, vectorized float4 -> ushort4
__global__ void cast_f32_bf16(const float4* __restrict__ in, ushort4* __restrict__ out, int n4) {
    int i = blockIdx.x * 256 + threadIdx.x;
    if (i < n4) {
        float4 f = in[i];
        ushort4 u;
        u.x = f2bits(f.x); u.y = f2bits(f.y); u.z = f2bits(f.z); u.w = f2bits(f.w);
        out[i] = u;
    }
}

// ---------------------------------------------------------------------------
// transpose+cast the three projection weights: W (K=1024,N=1024) fp32 -> Wt (N,K) bf16
__global__ void transpose_cast(const float* __restrict__ A, const float* __restrict__ B,
                               const float* __restrict__ C, bf16* __restrict__ Wt3) {
    const float* W = (blockIdx.z == 0) ? A : (blockIdx.z == 1) ? B : C;
    bf16* O = Wt3 + (size_t)blockIdx.z * (1024 * 1024);
    __shared__ float tile[32][33];
    int x = blockIdx.x * 32 + threadIdx.x;   // n
    int y0 = blockIdx.y * 32;                // k base
    for (int i = threadIdx.y; i < 32; i += 8)
        tile[i][threadIdx.x] = W[(size_t)(y0 + i) * 1024 + x];
    __syncthreads();
    int xo = blockIdx.y * 32 + threadIdx.x;  // k
    int yo = blockIdx.x * 32;                // n base
    for (int i = threadIdx.y; i < 32; i += 8)
        O[(size_t)(yo + i) * 1024 + xo] = __float2bfloat16(tile[threadIdx.x][i]);
}

// ---------------------------------------------------------------------------
// G = RF @ RF^T : (64,256)x(256,64) -> (64,64) fp32
__global__ void g_kernel(const float* __restrict__ RF, float* __restrict__ G) {
    int o = blockIdx.x * 256 + threadIdx.x;   // 0..4095
    int i = o >> 6, j = o & 63;
    const float4* a = (const float4*)(RF + (size_t)i * 256);
    const float4* b = (const float4*)(RF + (size_t)j * 256);
    float s = 0.f;
    for (int f = 0; f < 64; f++) {
        float4 x = a[f], y = b[f];
        s += x.x * y.x + x.y * y.y + x.z * y.z + x.w * y.w;
    }
    G[o] = s;
}

// ---------------------------------------------------------------------------
// Q/K/V projection GEMM: C = Xb @ W, 16384x1024x1024, bf16 MFMA 16x16x32.
// grid (8, 128, 3). XCD-swizzled block mapping: each XCD owns a 16-m-tile slab
// and walks all 8 n-tiles per m-tile (A-tile L2 reuse; B resident in L2).
// LDS XOR-swizzle: logical chunk c of row r stored at physical chunk c^(r&7)
// -> fragment ds_read_b128 is 2-way (free) instead of 16-way conflicted.
// z=0: Q (phi, row-major). z=1: K (phi, (b,h,n,d)). z=2: V (raw, (b,h,n,d)).
__global__ __launch_bounds__(256, 2) void gemm_qkv(
    const bf16* __restrict__ X, const bf16* __restrict__ Wt3,
    const float* __restrict__ bq, const float* __restrict__ bk, const float* __restrict__ bv,
    bf16* __restrict__ Qo, bf16* __restrict__ Ko, bf16* __restrict__ Vo)
{
    __shared__ bf16 As[128 * 64];
    __shared__ bf16 Bs[128 * 64];
    const int z = blockIdx.z;
    const int lid = blockIdx.x + (blockIdx.y << 3);
    const int xcd = lid & 7, seq = lid >> 3;
    const int m0 = (xcd * 16 + (seq >> 3)) * 128;
    const int n0 = (seq & 7) * 128;
    const int tid = threadIdx.x;
    const int w = tid >> 6, lane = tid & 63;
    const int lr = lane >> 3, lc = lane & 7;     // staging: 8 rows x 8 chunks(16B)
    const int sc = lc ^ lr;                      // swizzled global chunk
    const bf16* Wt = Wt3 + (size_t)z * (1024 * 1024);

    const bf16* ag = X  + (size_t)(m0 + w * 32 + lr) * 1024 + sc * 8;
    const bf16* bg = Wt + (size_t)(n0 + w * 32 + lr) * 1024 + sc * 8;
    bf16* al = As + (w * 32) * 64;
    bf16* bl = Bs + (w * 32) * 64;

    f32x4 acc[4][4];
#pragma unroll
    for (int i = 0; i < 4; i++)
#pragma unroll
        for (int j = 0; j < 4; j++) acc[i][j] = (f32x4){0.f, 0.f, 0.f, 0.f};

    const int lm = lane & 15, quad = lane >> 4;
    const int x0 = (quad ^ (lm & 7)) * 8;         // physical chunk, kk=0
    const int x1 = ((quad + 4) ^ (lm & 7)) * 8;   // physical chunk, kk=32
    const bf16* Ab = As + ((w >> 1) * 64 + lm) * 64;
    const bf16* Bb = Bs + ((w & 1) * 64 + lm) * 64;

    for (int k0 = 0; k0 < 1024; k0 += 64) {
#pragma unroll
        for (int j = 0; j < 4; j++) {
            gload_lds16(ag + (size_t)j * 8 * 1024 + k0, al + j * 8 * 64);
            gload_lds16(bg + (size_t)j * 8 * 1024 + k0, bl + j * 8 * 64);
        }
        __syncthreads();
#pragma unroll
        for (int kk = 0; kk < 2; kk++) {
            const int xo = kk ? x1 : x0;
            bf16x8 a[4], b[4];
#pragma unroll
            for (int i = 0; i < 4; i++) a[i] = *(const bf16x8*)(Ab + i * 16 * 64 + xo);
#pragma unroll
            for (int i = 0; i < 4; i++) b[i] = *(const bf16x8*)(Bb + i * 16 * 64 + xo);
#pragma unroll
            for (int mi = 0; mi < 4; mi++)
#pragma unroll
                for (int ni = 0; ni < 4; ni++)
                    acc[mi][ni] = __builtin_amdgcn_mfma_f32_16x16x32_bf16(
                        a[mi], b[ni], acc[mi][ni], 0, 0, 0);
        }
        __syncthreads();
    }

    const int wr = (w >> 1) * 64, wc = (w & 1) * 64;
    if (z == 0) {
#pragma unroll
        for (int ni = 0; ni < 4; ni++) {
            int col = n0 + wc + ni * 16 + lm;
            float bs = bq[col];
#pragma unroll
            for (int mi = 0; mi < 4; mi++) {
                int row0 = m0 + wr + mi * 16 + quad * 4;
#pragma unroll
                for (int r = 0; r < 4; r++) {
                    float v = acc[mi][ni][r] + bs;
                    v = (v > 0.f) ? (v + 1.f) : __expf(v);
                    Qo[(size_t)(row0 + r) * 1024 + col] = __float2bfloat16(v);
                }
            }
        }
    } else {
        const float* bias = (z == 1) ? bk : bv;
        bf16* Out = (z == 1) ? Ko : Vo;
#pragma unroll
        for (int ni = 0; ni < 4; ni++) {
            int col = n0 + wc + ni * 16 + lm;
            float bs = bias[col];
            int h = col >> 6, d = col & 63;
#pragma unroll
            for (int mi = 0; mi < 4; mi++) {
                int row0 = m0 + wr + mi * 16 + quad * 4;
#pragma unroll
                for (int r = 0; r < 4; r++) {
                    int row = row0 + r;
                    int b = row >> 12, n = row & 4095;
                    float v = acc[mi][ni][r] + bs;
                    if (z == 1) v = (v > 0.f) ? (v + 1.f) : __expf(v);
                    Out[(((size_t)(b * 16 + h) * 4096 + n) << 6) + d] = __float2bfloat16(v);
                }
            }
        }
    }
}

// ---------------------------------------------------------------------------
// S[b,h] = phi(k)^T @ v per (b,h) with K/V in (b,h,n,d) layout.
// grid (64, 8): bh x 512-row split; each block does two 256-row LDS tiles.
// Staging via global_load_lds (fully coalesced); compute = 4x4 outer products.
__global__ __launch_bounds__(256, 2) void s_kernel(const bf16* __restrict__ Kp,
                                                   const bf16* __restrict__ Vp,
                                                   float* __restrict__ Spart)
{
    __shared__ bf16 Ks[256 * 64];
    __shared__ bf16 Vs[256 * 64];
    const int bh = blockIdx.x, sp = blockIdx.y;
    const int t = threadIdx.x;
    const int w = t >> 6, lane = t & 63;
    const int eb = (t >> 4) * 4, db = (t & 15) * 4;
    const size_t base = ((size_t)bh * 4096 + sp * 512) * 64;

    float acc[4][4];
#pragma unroll
    for (int i = 0; i < 4; i++)
#pragma unroll
        for (int j = 0; j < 4; j++) acc[i][j] = 0.f;

    const unsigned short* ks = (const unsigned short*)Ks;
    const unsigned short* vs = (const unsigned short*)Vs;

    for (int tile = 0; tile < 2; tile++) {
        const bf16* kg = Kp + base + tile * (256 * 64) + (size_t)w * 4096 + lane * 8;
        const bf16* vg = Vp + base + tile * (256 * 64) + (size_t)w * 4096 + lane * 8;
#pragma unroll
        for (int r = 0; r < 8; r++) {
            gload_lds16(kg + r * 512, Ks + w * 4096 + r * 512);
            gload_lds16(vg + r * 512, Vs + w * 4096 + r * 512);
        }
        __syncthreads();
#pragma unroll 4
        for (int n = 0; n < 256; n++) {
            ushort4 ku = *(const ushort4*)(ks + n * 64 + eb);
            ushort4 vu = *(const ushort4*)(vs + n * 64 + db);
            float kf[4] = {bits2f(ku.x), bits2f(ku.y), bits2f(ku.z), bits2f(ku.w)};
            float vf[4] = {bits2f(vu.x), bits2f(vu.y), bits2f(vu.z), bits2f(vu.w)};
#pragma unroll
            for (int i = 0; i < 4; i++)
#pragma unroll
                for (int j = 0; j < 4; j++) acc[i][j] += kf[i] * vf[j];
        }
        __syncthreads();   // protect LDS before re-staging
    }

    float* spb = Spart + ((size_t)sp * 64 + bh) * 4096;
#pragma unroll
    for (int i = 0; i < 4; i++)
#pragma unroll
        for (int j = 0; j < 4; j++) spb[(eb + i) * 64 + db + j] = acc[i][j];
}

// reduce the 8 K-split partials: S[bh][4096] = sum_s Spart[s][bh][4096]
__global__ void reduce_s(const float* __restrict__ Spart, float* __restrict__ S) {
    int bh = blockIdx.x, t = threadIdx.x;
    for (int v = 0; v < 4; v++) {
        int idx = v * 1024 + t * 4;
        float4 a = {0.f, 0.f, 0.f, 0.f};
        for (int s2 = 0; s2 < 8; s2++) {
            float4 p = *(const float4*)&Spart[((size_t)s2 * 64 + bh) * 4096 + idx];
            a.x += p.x; a.y += p.y; a.z += p.z; a.w += p.w;
        }
        *(float4*)&S[(size_t)bh * 4096 + idx] = a;
    }
}

// M[b,h] = G @ S[b,h] : 64x64x64 per bh. grid 64, block 256.
__global__ __launch_bounds__(256) void m_kernel(const float* __restrict__ S,
                                                const float* __restrict__ G,
                                                float* __restrict__ M)
{
    __shared__ float Sl[4096];
    int bh = blockIdx.x, t = threadIdx.x;
    for (int i = t; i < 4096; i += 256) Sl[i] = S[(size_t)bh * 4096 + i];
    __syncthreads();
    int e = t >> 2, d0 = (t & 3) * 16;
    float acc[16];
#pragma unroll
    for (int j = 0; j < 16; j++) acc[j] = 0.f;
    for (int ep = 0; ep < 64; ep++) {
        float g = G[e * 64 + ep];
#pragma unroll
        for (int j = 0; j < 16; j++) acc[j] += g * Sl[ep * 64 + d0 + j];
    }
#pragma unroll
    for (int j = 0; j < 16; j++) M[(size_t)bh * 4096 + e * 64 + d0 + j] = acc[j];
}

// Fold M into Wo: Wo2t[b][c][h*64+e] = sum_d M[b,h][e][d] * Wo[h*64+d][c]
// (written transposed (N,K) for the final GEMM). grid 256 = (b,h,cblk), block 256.
__global__ __launch_bounds__(256) void fold_kernel(const float* __restrict__ M,
                                                   const float* __restrict__ Wo,
                                                   bf16* __restrict__ Wo2t)
{
    int x = blockIdx.x;
    int b = x >> 6, h = (x >> 2) & 15, cb = x & 3;
    __shared__ float Ml[4096];   // transposed: Ml[d*64 + e]
    int t = threadIdx.x;
    for (int i = t; i < 4096; i += 256) {
        int e = i >> 6, d = i & 63;
        Ml[d * 64 + e] = M[((size_t)b * 16 + h) * 4096 + i];
    }
    __syncthreads();
    int c = cb * 256 + t;
    float acc[64];
#pragma unroll
    for (int e = 0; e < 64; e++) acc[e] = 0.f;
    for (int d = 0; d < 64; d++) {
        float wo = Wo[(size_t)(h * 64 + d) * 1024 + c];
#pragma unroll
        for (int e = 0; e < 64; e++) acc[e] += Ml[d * 64 + e] * wo;
    }
    unsigned* outp = (unsigned*)(Wo2t + ((size_t)b * 1024 + c) * 1024 + h * 64);
#pragma unroll
    for (int e = 0; e < 64; e += 2) {
        unsigned lo = f2bits(acc[e]);
        unsigned hi = f2bits(acc[e + 1]);
        outp[e >> 1] = lo | (hi << 16);
    }
}

// ---------------------------------------------------------------------------
// Final GEMM: out = phi(q) @ Wo'_b + bo, fp32 output. grid (8,128).
// Same XCD swizzle + LDS XOR swizzle as gemm_qkv.
__global__ __launch_bounds__(256, 2) void gemm_out(
    const bf16* __restrict__ Qp, const bf16* __restrict__ Wo2t,
    const float* __restrict__ bo, float* __restrict__ Out)
{
    __shared__ bf16 As[128 * 64];
    __shared__ bf16 Bs[128 * 64];
    const int lid = blockIdx.x + (blockIdx.y << 3);
    const int xcd = lid & 7, seq = lid >> 3;
    const int m0 = (xcd * 16 + (seq >> 3)) * 128;
    const int n0 = (seq & 7) * 128;
    const int tid = threadIdx.x;
    const int w = tid >> 6, lane = tid & 63;
    const int lr = lane >> 3, lc = lane & 7;
    const int sc = lc ^ lr;
    const bf16* Wt = Wo2t + (size_t)(m0 >> 12) * (1024 * 1024);   // per-batch weights

    const bf16* ag = Qp + (size_t)(m0 + w * 32 + lr) * 1024 + sc * 8;
    const bf16* bg = Wt + (size_t)(n0 + w * 32 + lr) * 1024 + sc * 8;
    bf16* al = As + (w * 32) * 64;
    bf16* bl = Bs + (w * 32) * 64;

    f32x4 acc[4][4];
#pragma unroll
    for (int i = 0; i < 4; i++)
#pragma unroll
        for (int j = 0; j < 4; j++) acc[i][j] = (f32x4){0.f, 0.f, 0.f, 0.f};

    const int lm = lane & 15, quad = lane >> 4;
    const int x0 = (quad ^ (lm & 7)) * 8;
    const int x1 = ((quad + 4) ^ (lm & 7)) * 8;
    const bf16* Ab = As + ((w >> 1) * 64 + lm) * 64;
    const bf16* Bb = Bs + ((w & 1) * 64 + lm) * 64;

    for (int k0 = 0; k0 < 1024; k0 += 64) {
#pragma unroll
        for (int j = 0; j < 4; j++) {
            gload_lds16(ag + (size_t)j * 8 * 1024 + k0, al + j * 8 * 64);
            gload_lds16(bg + (size_t)j * 8 * 1024 + k0, bl + j * 8 * 64);
        }
        __syncthreads();
#pragma unroll
        for (int kk = 0; kk < 2; kk++) {
            const int xo = kk ? x1 : x0;
            bf16x8 a[4], b[4];
#pragma unroll
            for (int i = 0; i < 4; i++) a[i] = *(const bf16x8*)(Ab + i * 16 * 64 + xo);
#pragma unroll
            for (int i = 0; i < 4; i++) b[i] = *(const bf16x8*)(Bb + i * 16 * 64 + xo);
#pragma unroll
            for (int mi = 0; mi < 4; mi++)
#pragma unroll
                for (int ni = 0; ni < 4; ni++)
                    acc[mi][ni] = __builtin_amdgcn_mfma_f32_16x16x32_bf16(
                        a[mi], b[ni], acc[mi][ni], 0, 0, 0);
        }
        __syncthreads();
    }

    const int wr = (w >> 1) * 64, wc = (w & 1) * 64;
#pragma unroll
    for (int ni = 0; ni < 4; ni++) {
        int col = n0 + wc + ni * 16 + lm;
        float bs = bo[col];
#pragma unroll
        for (int mi = 0; mi < 4; mi++) {
            int row0 = m0 + wr + mi * 16 + quad * 4;
#pragma unroll
            for (int r = 0; r < 4; r++)
                Out[(size_t)(row0 + r) * 1024 + col] = acc[mi][ni][r] + bs;
        }
    }
}

// ---------------------------------------------------------------------------
extern "C" void kernel_launch(void* const* d_in, const int* in_sizes, int n_in,
                              void* d_out, int out_size, void* d_ws, size_t ws_size,
                              hipStream_t stream) {
    const float* x  = (const float*)d_in[0];
    const float* Wq = (const float*)d_in[1];
    const float* bq = (const float*)d_in[2];
    const float* Wk = (const float*)d_in[3];
    const float* bk = (const float*)d_in[4];
    const float* Wv = (const float*)d_in[5];
    const float* bv = (const float*)d_in[6];
    const float* Wo = (const float*)d_in[7];
    const float* bo = (const float*)d_in[8];
    const float* RF = (const float*)d_in[9];
    float* out = (float*)d_out;

    char* ws = (char*)d_ws;
    bf16*  Xb    = (bf16*) (ws);                           // 32 MB
    bf16*  Qp    = (bf16*) (ws + ((size_t)32  << 20));     // 32 MB (b*n, c)
    bf16*  Kp    = (bf16*) (ws + ((size_t)64  << 20));     // 32 MB (b,h,n,d)
    bf16*  Vp    = (bf16*) (ws + ((size_t)96  << 20));     // 32 MB (b,h,n,d)
    bf16*  Wt3   = (bf16*) (ws + ((size_t)128 << 20));     // 6 MB
    bf16*  Wo2t  = (bf16*) (ws + ((size_t)134 << 20));     // 8 MB
    float* Spart = (float*)(ws + ((size_t)142 << 20));     // 8 MB
    float* S     = (float*)(ws + ((size_t)150 << 20));     // 1 MB
    float* Mm    = (float*)(ws + ((size_t)151 << 20));     // 1 MB
    float* G     = (float*)(ws + ((size_t)152 << 20));     // 16 KB

    cast_f32_bf16<<<16384, 256, 0, stream>>>((const float4*)x, (ushort4*)Xb, 4194304);
    transpose_cast<<<dim3(32, 32, 3), dim3(32, 8), 0, stream>>>(Wq, Wk, Wv, Wt3);
    g_kernel<<<16, 256, 0, stream>>>(RF, G);
    gemm_qkv<<<dim3(8, 128, 3), 256, 0, stream>>>(Xb, Wt3, bq, bk, bv, Qp, Kp, Vp);
    s_kernel<<<dim3(64, 8), 256, 0, stream>>>(Kp, Vp, Spart);
    reduce_s<<<64, 256, 0, stream>>>(Spart, S);
    m_kernel<<<64, 256, 0, stream>>>(S, G, Mm);
    fold_kernel<<<256, 256, 0, stream>>>(Mm, Wo, Wo2t);
    gemm_out<<<dim3(8, 128), 256, 0, stream>>>(Qp, Wo2t, bo, out);
}

// Round 3
// 379.786 us; speedup vs baseline: 1.2420x; 1.0384x over previous
//
#include <hip/hip_runtime.h>
#include <hip/hip_bf16.h>
#include <cstdint>
#include <cstddef>

using bf16 = __hip_bfloat16;
typedef __attribute__((ext_vector_type(8))) __bf16 bf16x8;
typedef __attribute__((ext_vector_type(4))) float f32x4;

typedef const __attribute__((address_space(1))) void CGV;
typedef __attribute__((address_space(3))) void LDSV;

__device__ __forceinline__ void gload_lds16(const void* g, void* l) {
    // wave-uniform LDS base; HW writes lane i's 16B to base + i*16.
    __builtin_amdgcn_global_load_lds((CGV*)g, (LDSV*)l, 16, 0, 0);
}

__device__ __forceinline__ float bits2f(unsigned short u) {
    return __uint_as_float(((unsigned)u) << 16);
}
__device__ __forceinline__ unsigned short f2bits(float f) {
    return __builtin_bit_cast(unsigned short, __float2bfloat16(f));
}

// ---------------------------------------------------------------------------
// prep: one launch doing  [0,16384): cast x fp32->bf16
//                         [16384,19456): transpose+cast Wq/Wk/Wv -> (N,K) bf16
//                         [19456,19472): G = RF @ RF^T
__global__ __launch_bounds__(256) void prep_kernel(
    const float4* __restrict__ x4, ushort4* __restrict__ Xb4,
    const float* __restrict__ Wq, const float* __restrict__ Wk,
    const float* __restrict__ Wv, bf16* __restrict__ Wt3,
    const float* __restrict__ RF, float* __restrict__ G)
{
    const int bi = blockIdx.x;
    const int t = threadIdx.x;
    if (bi < 16384) {
        int i = bi * 256 + t;
        float4 f = x4[i];
        ushort4 u;
        u.x = f2bits(f.x); u.y = f2bits(f.y); u.z = f2bits(f.z); u.w = f2bits(f.w);
        Xb4[i] = u;
    } else if (bi < 19456) {
        int rem = bi - 16384;
        int z = rem >> 10;              // 0..2
        int r2 = rem & 1023;
        int bx = r2 & 31, by = r2 >> 5;
        const float* W = (z == 0) ? Wq : (z == 1) ? Wk : Wv;
        bf16* O = Wt3 + (size_t)z * (1024 * 1024);
        __shared__ float tile[32][33];
        int tx = t & 31, ty = t >> 5;   // 32 x 8
        int xg = bx * 32 + tx;          // n
        int y0 = by * 32;               // k base
        for (int i = ty; i < 32; i += 8)
            tile[i][tx] = W[(size_t)(y0 + i) * 1024 + xg];
        __syncthreads();
        int xo = by * 32 + tx;          // k
        int yo = bx * 32;               // n base
        for (int i = ty; i < 32; i += 8)
            O[(size_t)(yo + i) * 1024 + xo] = __float2bfloat16(tile[tx][i]);
    } else {
        int o = (bi - 19456) * 256 + t; // 0..4095
        int i = o >> 6, j = o & 63;
        const float4* a = (const float4*)(RF + (size_t)i * 256);
        const float4* b = (const float4*)(RF + (size_t)j * 256);
        float s = 0.f;
        for (int f = 0; f < 64; f++) {
            float4 xx = a[f], yy = b[f];
            s += xx.x * yy.x + xx.y * yy.y + xx.z * yy.z + xx.w * yy.w;
        }
        G[o] = s;
    }
}

// ---------------------------------------------------------------------------
// Q/K/V projection GEMM: C = Xb @ W, 16384x1024x1024, bf16 MFMA 16x16x32.
// XCD-swizzled blocks (A-tile L2 reuse), LDS XOR-swizzle (0 bank conflicts,
// verified R2). z=0: Q (phi, row-major). z=1: K (phi, (b,h,n,d)). z=2: V (raw).
__global__ __launch_bounds__(256, 4) void gemm_qkv(
    const bf16* __restrict__ X, const bf16* __restrict__ Wt3,
    const float* __restrict__ bq, const float* __restrict__ bk, const float* __restrict__ bv,
    bf16* __restrict__ Qo, bf16* __restrict__ Ko, bf16* __restrict__ Vo)
{
    __shared__ bf16 As[128 * 64];
    __shared__ bf16 Bs[128 * 64];
    const int z = blockIdx.z;
    const int lid = blockIdx.x + (blockIdx.y << 3);
    const int xcd = lid & 7, seq = lid >> 3;
    const int m0 = (xcd * 16 + (seq >> 3)) * 128;
    const int n0 = (seq & 7) * 128;
    const int tid = threadIdx.x;
    const int w = tid >> 6, lane = tid & 63;
    const int lr = lane >> 3, lc = lane & 7;     // staging: 8 rows x 8 chunks(16B)
    const int sc = lc ^ lr;                      // swizzled global chunk
    const bf16* Wt = Wt3 + (size_t)z * (1024 * 1024);

    const bf16* ag = X  + (size_t)(m0 + w * 32 + lr) * 1024 + sc * 8;
    const bf16* bg = Wt + (size_t)(n0 + w * 32 + lr) * 1024 + sc * 8;
    bf16* al = As + (w * 32) * 64;
    bf16* bl = Bs + (w * 32) * 64;

    f32x4 acc[4][4];
#pragma unroll
    for (int i = 0; i < 4; i++)
#pragma unroll
        for (int j = 0; j < 4; j++) acc[i][j] = (f32x4){0.f, 0.f, 0.f, 0.f};

    const int lm = lane & 15, quad = lane >> 4;
    const int x0 = (quad ^ (lm & 7)) * 8;         // physical chunk, kk=0
    const int x1 = ((quad + 4) ^ (lm & 7)) * 8;   // physical chunk, kk=32
    const bf16* Ab = As + ((w >> 1) * 64 + lm) * 64;
    const bf16* Bb = Bs + ((w & 1) * 64 + lm) * 64;

    for (int k0 = 0; k0 < 1024; k0 += 64) {
#pragma unroll
        for (int j = 0; j < 4; j++) {
            gload_lds16(ag + (size_t)j * 8 * 1024 + k0, al + j * 8 * 64);
            gload_lds16(bg + (size_t)j * 8 * 1024 + k0, bl + j * 8 * 64);
        }
        __syncthreads();
#pragma unroll
        for (int kk = 0; kk < 2; kk++) {
            const int xo = kk ? x1 : x0;
            bf16x8 a[4], b[4];
#pragma unroll
            for (int i = 0; i < 4; i++) a[i] = *(const bf16x8*)(Ab + i * 16 * 64 + xo);
#pragma unroll
            for (int i = 0; i < 4; i++) b[i] = *(const bf16x8*)(Bb + i * 16 * 64 + xo);
#pragma unroll
            for (int mi = 0; mi < 4; mi++)
#pragma unroll
                for (int ni = 0; ni < 4; ni++)
                    acc[mi][ni] = __builtin_amdgcn_mfma_f32_16x16x32_bf16(
                        a[mi], b[ni], acc[mi][ni], 0, 0, 0);
        }
        __syncthreads();
    }

    const int wr = (w >> 1) * 64, wc = (w & 1) * 64;
    if (z == 0) {
#pragma unroll
        for (int ni = 0; ni < 4; ni++) {
            int col = n0 + wc + ni * 16 + lm;
            float bs = bq[col];
#pragma unroll
            for (int mi = 0; mi < 4; mi++) {
                int row0 = m0 + wr + mi * 16 + quad * 4;
#pragma unroll
                for (int r = 0; r < 4; r++) {
                    float v = acc[mi][ni][r] + bs;
                    v = (v > 0.f) ? (v + 1.f) : __expf(v);
                    Qo[(size_t)(row0 + r) * 1024 + col] = __float2bfloat16(v);
                }
            }
        }
    } else {
        const float* bias = (z == 1) ? bk : bv;
        bf16* Out = (z == 1) ? Ko : Vo;
#pragma unroll
        for (int ni = 0; ni < 4; ni++) {
            int col = n0 + wc + ni * 16 + lm;
            float bs = bias[col];
            int h = col >> 6, d = col & 63;
#pragma unroll
            for (int mi = 0; mi < 4; mi++) {
                int row0 = m0 + wr + mi * 16 + quad * 4;
#pragma unroll
                for (int r = 0; r < 4; r++) {
                    int row = row0 + r;
                    int b = row >> 12, n = row & 4095;
                    float v = acc[mi][ni][r] + bs;
                    if (z == 1) v = (v > 0.f) ? (v + 1.f) : __expf(v);
                    Out[(((size_t)(b * 16 + h) * 4096 + n) << 6) + d] = __float2bfloat16(v);
                }
            }
        }
    }
}

// ---------------------------------------------------------------------------
// S[b,h] = phi(k)^T @ v per (b,h) with K/V in (b,h,n,d) layout.
// grid (64, 8): bh x 512-row split; two 256-row LDS tiles per block.
__global__ __launch_bounds__(256, 2) void s_kernel(const bf16* __restrict__ Kp,
                                                   const bf16* __restrict__ Vp,
                                                   float* __restrict__ Spart)
{
    __shared__ bf16 Ks[256 * 64];
    __shared__ bf16 Vs[256 * 64];
    const int bh = blockIdx.x, sp = blockIdx.y;
    const int t = threadIdx.x;
    const int w = t >> 6, lane = t & 63;
    const int eb = (t >> 4) * 4, db = (t & 15) * 4;
    const size_t base = ((size_t)bh * 4096 + sp * 512) * 64;

    float acc[4][4];
#pragma unroll
    for (int i = 0; i < 4; i++)
#pragma unroll
        for (int j = 0; j < 4; j++) acc[i][j] = 0.f;

    const unsigned short* ks = (const unsigned short*)Ks;
    const unsigned short* vs = (const unsigned short*)Vs;

    for (int tile = 0; tile < 2; tile++) {
        const bf16* kg = Kp + base + tile * (256 * 64) + (size_t)w * 4096 + lane * 8;
        const bf16* vg = Vp + base + tile * (256 * 64) + (size_t)w * 4096 + lane * 8;
#pragma unroll
        for (int r = 0; r < 8; r++) {
            gload_lds16(kg + r * 512, Ks + w * 4096 + r * 512);
            gload_lds16(vg + r * 512, Vs + w * 4096 + r * 512);
        }
        __syncthreads();
#pragma unroll 4
        for (int n = 0; n < 256; n++) {
            ushort4 ku = *(const ushort4*)(ks + n * 64 + eb);
            ushort4 vu = *(const ushort4*)(vs + n * 64 + db);
            float kf[4] = {bits2f(ku.x), bits2f(ku.y), bits2f(ku.z), bits2f(ku.w)};
            float vf[4] = {bits2f(vu.x), bits2f(vu.y), bits2f(vu.z), bits2f(vu.w)};
#pragma unroll
            for (int i = 0; i < 4; i++)
#pragma unroll
                for (int j = 0; j < 4; j++) acc[i][j] += kf[i] * vf[j];
        }
        __syncthreads();   // protect LDS before re-staging
    }

    float* spb = Spart + ((size_t)sp * 64 + bh) * 4096;
#pragma unroll
    for (int i = 0; i < 4; i++)
#pragma unroll
        for (int j = 0; j < 4; j++) spb[(eb + i) * 64 + db + j] = acc[i][j];
}

// ---------------------------------------------------------------------------
// fold2: fused reduce_s + (M = G@S) + fold-into-Wo.
// grid 256 = (b, h, cblk): Wo2t[b][c][h*64+e] = sum_d (G@S[b,h])[e][d] * Wo[h*64+d][c]
__global__ __launch_bounds__(256) void fold2_kernel(const float* __restrict__ Spart,
                                                    const float* __restrict__ G,
                                                    const float* __restrict__ Wo,
                                                    bf16* __restrict__ Wo2t)
{
    __shared__ float Sl[4096];   // reduced S[e*64+d]
    __shared__ float Ml[4096];   // transposed M: Ml[d*64+e]
    const int xb = blockIdx.x;
    const int b = xb >> 6, h = (xb >> 2) & 15, cb = xb & 3;
    const int bh = b * 16 + h;
    const int t = threadIdx.x;

    // reduce 8 K-split partials into Sl
    for (int i = t; i < 4096; i += 256) {
        float s = 0.f;
#pragma unroll
        for (int sp = 0; sp < 8; sp++)
            s += Spart[((size_t)sp * 64 + bh) * 4096 + i];
        Sl[i] = s;
    }
    __syncthreads();

    // M = G @ S ; write transposed into Ml. thread t: e = t>>2, 16 d's.
    {
        const int e = t >> 2, dblk = (t & 3) * 16;
        float acc[16];
#pragma unroll
        for (int j = 0; j < 16; j++) acc[j] = 0.f;
        for (int ep = 0; ep < 64; ep++) {
            float g = G[e * 64 + ep];
#pragma unroll
            for (int j = 0; j < 16; j++) acc[j] += g * Sl[ep * 64 + dblk + j];
        }
        __syncthreads();   // done reading Sl region? (Ml separate, but keep order safe)
#pragma unroll
        for (int j = 0; j < 16; j++) Ml[(dblk + j) * 64 + e] = acc[j];
    }
    __syncthreads();

    // fold: c = cb*256 + t
    const int c = cb * 256 + t;
    float acc[64];
#pragma unroll
    for (int e = 0; e < 64; e++) acc[e] = 0.f;
    for (int d = 0; d < 64; d++) {
        float wo = Wo[(size_t)(h * 64 + d) * 1024 + c];
#pragma unroll
        for (int e = 0; e < 64; e++) acc[e] += Ml[d * 64 + e] * wo;
    }
    unsigned* outp = (unsigned*)(Wo2t + ((size_t)b * 1024 + c) * 1024 + h * 64);
#pragma unroll
    for (int e = 0; e < 64; e += 2) {
        unsigned lo = f2bits(acc[e]);
        unsigned hi = f2bits(acc[e + 1]);
        outp[e >> 1] = lo | (hi << 16);
    }
}

// ---------------------------------------------------------------------------
// Final GEMM: out = phi(q) @ Wo'_b + bo, fp32 output. grid (8,128).
__global__ __launch_bounds__(256, 4) void gemm_out(
    const bf16* __restrict__ Qp, const bf16* __restrict__ Wo2t,
    const float* __restrict__ bo, float* __restrict__ Out)
{
    __shared__ bf16 As[128 * 64];
    __shared__ bf16 Bs[128 * 64];
    const int lid = blockIdx.x + (blockIdx.y << 3);
    const int xcd = lid & 7, seq = lid >> 3;
    const int m0 = (xcd * 16 + (seq >> 3)) * 128;
    const int n0 = (seq & 7) * 128;
    const int tid = threadIdx.x;
    const int w = tid >> 6, lane = tid & 63;
    const int lr = lane >> 3, lc = lane & 7;
    const int sc = lc ^ lr;
    const bf16* Wt = Wo2t + (size_t)(m0 >> 12) * (1024 * 1024);   // per-batch weights

    const bf16* ag = Qp + (size_t)(m0 + w * 32 + lr) * 1024 + sc * 8;
    const bf16* bg = Wt + (size_t)(n0 + w * 32 + lr) * 1024 + sc * 8;
    bf16* al = As + (w * 32) * 64;
    bf16* bl = Bs + (w * 32) * 64;

    f32x4 acc[4][4];
#pragma unroll
    for (int i = 0; i < 4; i++)
#pragma unroll
        for (int j = 0; j < 4; j++) acc[i][j] = (f32x4){0.f, 0.f, 0.f, 0.f};

    const int lm = lane & 15, quad = lane >> 4;
    const int x0 = (quad ^ (lm & 7)) * 8;
    const int x1 = ((quad + 4) ^ (lm & 7)) * 8;
    const bf16* Ab = As + ((w >> 1) * 64 + lm) * 64;
    const bf16* Bb = Bs + ((w & 1) * 64 + lm) * 64;

    for (int k0 = 0; k0 < 1024; k0 += 64) {
#pragma unroll
        for (int j = 0; j < 4; j++) {
            gload_lds16(ag + (size_t)j * 8 * 1024 + k0, al + j * 8 * 64);
            gload_lds16(bg + (size_t)j * 8 * 1024 + k0, bl + j * 8 * 64);
        }
        __syncthreads();
#pragma unroll
        for (int kk = 0; kk < 2; kk++) {
            const int xo = kk ? x1 : x0;
            bf16x8 a[4], b[4];
#pragma unroll
            for (int i = 0; i < 4; i++) a[i] = *(const bf16x8*)(Ab + i * 16 * 64 + xo);
#pragma unroll
            for (int i = 0; i < 4; i++) b[i] = *(const bf16x8*)(Bb + i * 16 * 64 + xo);
#pragma unroll
            for (int mi = 0; mi < 4; mi++)
#pragma unroll
                for (int ni = 0; ni < 4; ni++)
                    acc[mi][ni] = __builtin_amdgcn_mfma_f32_16x16x32_bf16(
                        a[mi], b[ni], acc[mi][ni], 0, 0, 0);
        }
        __syncthreads();
    }

    const int wr = (w >> 1) * 64, wc = (w & 1) * 64;
#pragma unroll
    for (int ni = 0; ni < 4; ni++) {
        int col = n0 + wc + ni * 16 + lm;
        float bs = bo[col];
#pragma unroll
        for (int mi = 0; mi < 4; mi++) {
            int row0 = m0 + wr + mi * 16 + quad * 4;
#pragma unroll
            for (int r = 0; r < 4; r++)
                Out[(size_t)(row0 + r) * 1024 + col] = acc[mi][ni][r] + bs;
        }
    }
}

// ---------------------------------------------------------------------------
extern "C" void kernel_launch(void* const* d_in, const int* in_sizes, int n_in,
                              void* d_out, int out_size, void* d_ws, size_t ws_size,
                              hipStream_t stream) {
    const float* x  = (const float*)d_in[0];
    const float* Wq = (const float*)d_in[1];
    const float* bq = (const float*)d_in[2];
    const float* Wk = (const float*)d_in[3];
    const float* bk = (const float*)d_in[4];
    const float* Wv = (const float*)d_in[5];
    const float* bv = (const float*)d_in[6];
    const float* Wo = (const float*)d_in[7];
    const float* bo = (const float*)d_in[8];
    const float* RF = (const float*)d_in[9];
    float* out = (float*)d_out;

    char* ws = (char*)d_ws;
    bf16*  Xb    = (bf16*) (ws);                           // 32 MB
    bf16*  Qp    = (bf16*) (ws + ((size_t)32  << 20));     // 32 MB (b*n, c)
    bf16*  Kp    = (bf16*) (ws + ((size_t)64  << 20));     // 32 MB (b,h,n,d)
    bf16*  Vp    = (bf16*) (ws + ((size_t)96  << 20));     // 32 MB (b,h,n,d)
    bf16*  Wt3   = (bf16*) (ws + ((size_t)128 << 20));     // 6 MB
    bf16*  Wo2t  = (bf16*) (ws + ((size_t)134 << 20));     // 8 MB
    float* Spart = (float*)(ws + ((size_t)142 << 20));     // 8 MB
    float* G     = (float*)(ws + ((size_t)152 << 20));     // 16 KB

    prep_kernel<<<19472, 256, 0, stream>>>((const float4*)x, (ushort4*)Xb,
                                           Wq, Wk, Wv, Wt3, RF, G);
    gemm_qkv<<<dim3(8, 128, 3), 256, 0, stream>>>(Xb, Wt3, bq, bk, bv, Qp, Kp, Vp);
    s_kernel<<<dim3(64, 8), 256, 0, stream>>>(Kp, Vp, Spart);
    fold2_kernel<<<256, 256, 0, stream>>>(Spart, G, Wo, Wo2t);
    gemm_out<<<dim3(8, 128), 256, 0, stream>>>(Qp, Wo2t, bo, out);
}